// Round 1
// baseline (783.930 us; speedup 1.0000x reference)
//
#include <hip/hip_runtime.h>

// MultiScaleTimeMixer: B=64, T=512, C=512, T2=256
// Layout strategy: keep everything in [B, T, C] (x's native layout).
//  Xn[b]   = ((x[b]-mu_b)*istd_b) .* gT + bT          [512x512] per batch
//  Y1[b]   = hsw(tril(w1) @ Xn[b] + b1[row])           [512x512]
//  out_y   = tril(w2) @ Y1[b] + b2[row]   -> transposed store out[b,c,0:512]
//  Z1[b]   = xr[b](256x1024) @ Wt(1024x512) + cb[col]  [256x512]
//  Z3[b]   = hsw(tril(w3) @ Z1[b] + b3[row])           [256x512]
//  out_z   = tril(w4) @ Z3[b] + b4[row]   -> transposed store out[b,c,512:768]

#define NB 64

// ---------------- per-batch mean/var (two-stage, deterministic) ----------------
__global__ void stats_partial_k(const float* __restrict__ x, float* __restrict__ part) {
  int bb = blockIdx.x;              // 0..255 = 4 blocks per batch
  int b = bb >> 2, q = bb & 3;
  const float4* xb = (const float4*)(x + (size_t)b * 262144 + (size_t)q * 65536);
  float s = 0.f, ss = 0.f;
  for (int it = 0; it < 64; ++it) {
    float4 v = xb[threadIdx.x + 256 * it];
    s  += (v.x + v.y) + (v.z + v.w);
    ss += (v.x * v.x + v.y * v.y) + (v.z * v.z + v.w * v.w);
  }
  __shared__ float ls[256], lss[256];
  ls[threadIdx.x] = s; lss[threadIdx.x] = ss;
  __syncthreads();
  for (int off = 128; off > 0; off >>= 1) {
    if (threadIdx.x < off) {
      ls[threadIdx.x]  += ls[threadIdx.x + off];
      lss[threadIdx.x] += lss[threadIdx.x + off];
    }
    __syncthreads();
  }
  if (threadIdx.x == 0) { part[bb * 2] = ls[0]; part[bb * 2 + 1] = lss[0]; }
}

__global__ void stats_final_k(const float* __restrict__ part, float* __restrict__ stats) {
  int b = threadIdx.x;
  if (b < NB) {
    float s = 0.f, ss = 0.f;
    for (int q = 0; q < 4; ++q) { s += part[(b * 4 + q) * 2]; ss += part[(b * 4 + q) * 2 + 1]; }
    float mean = s * (1.f / 262144.f);
    float var  = ss * (1.f / 262144.f) - mean * mean;
    stats[b * 2]     = mean;
    stats[b * 2 + 1] = rsqrtf(var + 1e-5f);
  }
}

// ---------------- transpose gamma/beta: gT[t][c] = g[c][t] ----------------
__global__ void transpose2_k(const float* __restrict__ g, const float* __restrict__ be,
                             float* __restrict__ gT, float* __restrict__ bT) {
  __shared__ float tg[32][33], tb[32][33];
  int bx = blockIdx.x * 32;
  int by = blockIdx.y * 32;
  int lx = threadIdx.x & 31;
  int ly4 = (threadIdx.x >> 5) * 4;
  for (int q = 0; q < 4; ++q) {
    int r = by + ly4 + q;
    tg[ly4 + q][lx] = g[(size_t)r * 512 + bx + lx];
    tb[ly4 + q][lx] = be[(size_t)r * 512 + bx + lx];
  }
  __syncthreads();
  for (int q = 0; q < 4; ++q) {
    int r = bx + ly4 + q;    // dest row = source col
    gT[(size_t)r * 512 + by + lx] = tg[lx][ly4 + q];
    bT[(size_t)r * 512 + by + lx] = tb[lx][ly4 + q];
  }
}

// ---------------- normalize: Xn[b][t][c] ----------------
__global__ void normalize_k(const float* __restrict__ x, const float* __restrict__ gT,
                            const float* __restrict__ bT, const float* __restrict__ stats,
                            float* __restrict__ xn) {
  int idx = blockIdx.x * 256 + threadIdx.x;   // float4 index over 64*512*512/4
  int b = idx >> 16;
  int tc = idx & 65535;
  float mean = stats[b * 2], istd = stats[b * 2 + 1];
  float4 v  = ((const float4*)x)[idx];
  float4 gv = ((const float4*)gT)[tc];
  float4 bv = ((const float4*)bT)[tc];
  float4 o;
  o.x = (v.x - mean) * istd * gv.x + bv.x;
  o.y = (v.y - mean) * istd * gv.y + bv.y;
  o.z = (v.z - mean) * istd * gv.z + bv.z;
  o.w = (v.w - mean) * istd * gv.w + bv.w;
  ((float4*)xn)[idx] = o;
}

// ---------------- conv weight reindex: Wt[k*512+i][o] = conv_w[o][i][k] ----------------
__global__ void prep_wt_k(const float* __restrict__ cw, float* __restrict__ Wt) {
  int idx = blockIdx.x * 256 + threadIdx.x;   // 1024*512
  int o = idx & 511;
  int m = idx >> 9;
  int i = m & 511;
  int k = m >> 9;
  Wt[idx] = cw[(size_t)o * 1024 + i * 2 + k];
}

// ---------------- tiled f32 GEMM: C[b] = A @ B[b], 128x128 tile, 8x8/thread ----------------
template <bool MASK_A, bool HSW, bool ROW_BIAS, bool COL_BIAS, bool TRANS_OUT>
__global__ __launch_bounds__(256) void gemm_f32_k(
    const float* __restrict__ A, long sAb,
    const float* __restrict__ Bm, long sBb,
    float* __restrict__ Cm, long sCb,
    const float* __restrict__ bias,
    int M, int N, int K, int ldc_col, int c_off) {
  __shared__ __align__(16) float As[16][132];
  __shared__ __align__(16) float Bs[16][128];
  const int tid = threadIdx.x;
  const int tx = tid & 15, ty = tid >> 4;
  const int bm = blockIdx.x * 128, bn = blockIdx.y * 128, bz = blockIdx.z;
  const float* Ab = A + (size_t)bz * sAb;
  const float* Bb = Bm + (size_t)bz * sBb;

  float acc[8][8];
#pragma unroll
  for (int i = 0; i < 8; ++i)
#pragma unroll
    for (int j = 0; j < 8; ++j) acc[i][j] = 0.f;

  const int lar = tid >> 4;   // A-load base row (0..15)
  const int lak = tid & 15;   // A-load k
  const int lbk = tid >> 7;   // B-load base k (0..1)
  const int lbc = tid & 127;  // B-load col

  for (int k0 = 0; k0 < K; k0 += 16) {
#pragma unroll
    for (int it = 0; it < 8; ++it) {
      int r = lar + 16 * it;
      int grow = bm + r, gk = k0 + lak;
      float v = Ab[(size_t)grow * K + gk];
      if (MASK_A) v = (gk <= grow) ? v : 0.f;   // tril mask
      As[lak][r] = v;
    }
#pragma unroll
    for (int it = 0; it < 8; ++it) {
      int kk = lbk + 2 * it;
      Bs[kk][lbc] = Bb[(size_t)(k0 + kk) * N + bn + lbc];
    }
    __syncthreads();
#pragma unroll
    for (int k = 0; k < 16; ++k) {
      float4 a0 = *(const float4*)&As[k][ty * 8];
      float4 a1 = *(const float4*)&As[k][ty * 8 + 4];
      float4 b0 = *(const float4*)&Bs[k][tx * 4];
      float4 b1 = *(const float4*)&Bs[k][tx * 4 + 64];
      float av[8] = {a0.x, a0.y, a0.z, a0.w, a1.x, a1.y, a1.z, a1.w};
      float bv[8] = {b0.x, b0.y, b0.z, b0.w, b1.x, b1.y, b1.z, b1.w};
#pragma unroll
      for (int i = 0; i < 8; ++i)
#pragma unroll
        for (int j = 0; j < 8; ++j) acc[i][j] = fmaf(av[i], bv[j], acc[i][j]);
    }
    __syncthreads();
  }

  // epilogue: bias -> hardswish -> store
#pragma unroll
  for (int i = 0; i < 8; ++i) {
    int row = bm + ty * 8 + i;
    float rb = ROW_BIAS ? bias[row] : 0.f;
#pragma unroll
    for (int j = 0; j < 8; ++j) {
      int col = bn + ((j < 4) ? tx * 4 + j : 64 + tx * 4 + (j - 4));
      float v = acc[i][j] + rb;
      if (COL_BIAS) v += bias[col];
      if (HSW) {
        float t = v + 3.f;
        t = fminf(fmaxf(t, 0.f), 6.f);
        v = v * t * (1.f / 6.f);
      }
      acc[i][j] = v;
    }
  }
  float* Cb = Cm + (size_t)bz * sCb;
  if (!TRANS_OUT) {
#pragma unroll
    for (int i = 0; i < 8; ++i) {
      int row = bm + ty * 8 + i;
      float4 v0 = make_float4(acc[i][0], acc[i][1], acc[i][2], acc[i][3]);
      float4 v1 = make_float4(acc[i][4], acc[i][5], acc[i][6], acc[i][7]);
      *(float4*)&Cb[(size_t)row * N + bn + tx * 4] = v0;
      *(float4*)&Cb[(size_t)row * N + bn + 64 + tx * 4] = v1;
    }
  } else {
    // out[b][col][c_off + row], row contiguous -> float4 down rows
#pragma unroll
    for (int j = 0; j < 8; ++j) {
      int col = bn + ((j < 4) ? tx * 4 + j : 64 + tx * 4 + (j - 4));
      float4 v0 = make_float4(acc[0][j], acc[1][j], acc[2][j], acc[3][j]);
      float4 v1 = make_float4(acc[4][j], acc[5][j], acc[6][j], acc[7][j]);
      size_t base = (size_t)col * ldc_col + c_off + bm + ty * 8;
      *(float4*)&Cb[base] = v0;
      *(float4*)&Cb[base + 4] = v1;
    }
  }
}

extern "C" void kernel_launch(void* const* d_in, const int* in_sizes, int n_in,
                              void* d_out, int out_size, void* d_ws, size_t ws_size,
                              hipStream_t stream) {
  const float* x  = (const float*)d_in[0];
  const float* g  = (const float*)d_in[1];
  const float* be = (const float*)d_in[2];
  const float* w1 = (const float*)d_in[3];
  const float* b1 = (const float*)d_in[4];
  const float* w2 = (const float*)d_in[5];
  const float* b2 = (const float*)d_in[6];
  const float* cw = (const float*)d_in[7];
  const float* cb = (const float*)d_in[8];
  const float* w3 = (const float*)d_in[9];
  const float* b3 = (const float*)d_in[10];
  const float* w4 = (const float*)d_in[11];
  const float* b4 = (const float*)d_in[12];
  float* out = (float*)d_out;

  char* ws = (char*)d_ws;
  float* stats = (float*)(ws);                       // 512 B
  float* part  = (float*)(ws + 512);                 // 2 KB
  float* Wt    = (float*)(ws + (1 << 20));           // 2 MB   [1024x512]
  float* gT    = (float*)(ws + (3 << 20));           // 1 MB
  float* bT    = (float*)(ws + (4 << 20));           // 1 MB
  float* bufA  = (float*)(ws + (5 << 20));           // 64 MB  (Xn, later Z1)
  float* bufB  = (float*)(ws + (size_t)(69) * (1 << 20)); // 64 MB (hsw(Y1), later Z3)
  // total ws use: 133 MB

  stats_partial_k<<<256, 256, 0, stream>>>(x, part);
  stats_final_k<<<1, 64, 0, stream>>>(part, stats);
  transpose2_k<<<dim3(16, 16), 256, 0, stream>>>(g, be, gT, bT);
  normalize_k<<<16384, 256, 0, stream>>>(x, gT, bT, stats, bufA);
  prep_wt_k<<<2048, 256, 0, stream>>>(cw, Wt);

  // GEMM1: bufB = hsw(tril(w1) @ Xn + b1)            M=512 N=512 K=512
  gemm_f32_k<true, true, true, false, false><<<dim3(4, 4, NB), 256, 0, stream>>>(
      w1, 0, bufA, 262144, bufB, 262144, b1, 512, 512, 512, 0, 0);
  // GEMM2: out[:, :, 0:512] = (tril(w2) @ bufB + b2)^T   (transposed store)
  gemm_f32_k<true, false, true, false, true><<<dim3(4, 4, NB), 256, 0, stream>>>(
      w2, 0, bufB, 262144, out, 393216, b2, 512, 512, 512, 768, 0);
  // GEMM3 (conv): bufA = x_r(256x1024) @ Wt + conv_b[col]   M=256 N=512 K=1024
  gemm_f32_k<false, false, false, true, false><<<dim3(2, 4, NB), 256, 0, stream>>>(
      x, 262144, Wt, 0, bufA, 131072, cb, 256, 512, 1024, 0, 0);
  // GEMM4: bufB = hsw(tril(w3) @ bufA + b3)           M=256 N=512 K=256
  gemm_f32_k<true, true, true, false, false><<<dim3(2, 4, NB), 256, 0, stream>>>(
      w3, 0, bufA, 131072, bufB, 131072, b3, 256, 512, 256, 0, 0);
  // GEMM5: out[:, :, 512:768] = (tril(w4) @ bufB + b4)^T
  gemm_f32_k<true, false, true, false, true><<<dim3(2, 4, NB), 256, 0, stream>>>(
      w4, 0, bufB, 131072, out, 393216, b4, 256, 512, 256, 768, 512);
}

// Round 2
// 178.328 us; speedup vs baseline: 4.3960x; 4.3960x over previous
//
#include <hip/hip_runtime.h>
#include <hip/hip_bf16.h>

// MultiScaleTimeMixer: B=64, T=512, C=512, T2=256
// bf16 MFMA pipeline, all intermediates stored TRANSPOSED ([N x K] for the next GEMM):
//  XnT[b][c][t]  = normalize(x)          (bf16)   <- B-operand of GEMM1
//  xbf[b][t][c]  = bf16(x)                        <- A-operand of GEMM3 (conv-as-GEMM)
//  GEMM1: Y1T = (hsw(tril(w1) @ Xn + b1))^T  [c][i]   bf16
//  GEMM2: out[b][c][0:512]   = (tril(w2) @ Y1 + b2)^T  f32
//  GEMM3: Z1T = (xr @ Wt + cb)^T            [o][t']    bf16
//  GEMM4: Z3T = (hsw(tril(w3) @ Z1 + b3))^T [c][i]     bf16
//  GEMM5: out[b][c][512:768] = (tril(w4) @ Z3 + b4)^T  f32

#define NB 64

typedef __bf16 bf16x8 __attribute__((ext_vector_type(8)));
typedef __bf16 bf16x4 __attribute__((ext_vector_type(4)));
typedef float f32x4 __attribute__((ext_vector_type(4)));

// ---------------- per-batch mean/var ----------------
__global__ void stats_partial_k(const float* __restrict__ x, float* __restrict__ part) {
  int bb = blockIdx.x;  // 256 = 4 per batch
  int b = bb >> 2, q = bb & 3;
  const float4* xb = (const float4*)(x + (size_t)b * 262144 + (size_t)q * 65536);
  float s = 0.f, ss = 0.f;
  for (int it = 0; it < 64; ++it) {
    float4 v = xb[threadIdx.x + 256 * it];
    s += (v.x + v.y) + (v.z + v.w);
    ss += (v.x * v.x + v.y * v.y) + (v.z * v.z + v.w * v.w);
  }
  __shared__ float ls[256], lss[256];
  ls[threadIdx.x] = s; lss[threadIdx.x] = ss;
  __syncthreads();
  for (int off = 128; off > 0; off >>= 1) {
    if (threadIdx.x < off) {
      ls[threadIdx.x] += ls[threadIdx.x + off];
      lss[threadIdx.x] += lss[threadIdx.x + off];
    }
    __syncthreads();
  }
  if (threadIdx.x == 0) { part[bb * 2] = ls[0]; part[bb * 2 + 1] = lss[0]; }
}

__global__ void stats_final_k(const float* __restrict__ part, float* __restrict__ stats) {
  int b = threadIdx.x;
  if (b < NB) {
    float s = 0.f, ss = 0.f;
    for (int q = 0; q < 4; ++q) { s += part[(b * 4 + q) * 2]; ss += part[(b * 4 + q) * 2 + 1]; }
    float mean = s * (1.f / 262144.f);
    float var = ss * (1.f / 262144.f) - mean * mean;
    stats[b * 2] = mean;
    stats[b * 2 + 1] = rsqrtf(var + 1e-5f);
  }
}

// ---- normalize+transpose: XnT[b][c][t] (bf16), plus straight bf16 cast xbf[b][t][c] ----
__global__ void norm_trans_k(const float* __restrict__ x, const float* __restrict__ g,
                             const float* __restrict__ be, const float* __restrict__ stats,
                             __bf16* __restrict__ XnT, __bf16* __restrict__ xbf) {
  __shared__ float ls[32][33];
  int b = blockIdx.z;
  int bx = blockIdx.x * 32;  // c tile
  int by = blockIdx.y * 32;  // t tile
  int tx = threadIdx.x, ty = threadIdx.y;
  float mean = stats[b * 2], istd = stats[b * 2 + 1];
  const float* xb = x + (size_t)b * 262144;
#pragma unroll
  for (int q = 0; q < 4; ++q) {
    int tl = ty + q * 8;                      // t local
    int t = by + tl, c = bx + tx;
    float v = xb[(size_t)t * 512 + c];
    xbf[(size_t)b * 262144 + (size_t)t * 512 + c] = (__bf16)v;
    ls[tl][tx] = v;
  }
  __syncthreads();
#pragma unroll
  for (int q = 0; q < 4; ++q) {
    int cl = ty + q * 8;                      // c local
    int c = bx + cl, t = by + tx;
    float xh = (ls[tx][cl] - mean) * istd;
    float gv = g[(size_t)c * 512 + t];        // positional [C,T] view of ln_gamma[T,C]
    float bv = be[(size_t)c * 512 + t];
    XnT[(size_t)b * 262144 + (size_t)c * 512 + t] = (__bf16)(xh * gv + bv);
  }
}

// ---- weight prep: tril-mask + bf16 cast, o[i*n+j] ----
__global__ void wmask_k(const float* __restrict__ w, __bf16* __restrict__ o, int logn) {
  int idx = blockIdx.x * 256 + threadIdx.x;
  int i = idx >> logn, j = idx & ((1 << logn) - 1);
  o[idx] = (__bf16)(j <= i ? w[idx] : 0.f);
}

// ---- conv weight: WtT[o][k*512+i] = cw[o][i*2+k]  (B^T layout [N=512][K=1024]) ----
__global__ void wtprep_k(const float* __restrict__ cw, __bf16* __restrict__ WtT) {
  int idx = blockIdx.x * 256 + threadIdx.x;  // 512*1024
  int o = idx >> 10, r = idx & 1023;
  int i = r & 511, k = r >> 9;
  WtT[idx] = (__bf16)cw[(size_t)o * 1024 + i * 2 + k];
}

// ---------------- MFMA GEMM: D^T store. A [MxK] rm, Bt [NxK] rm, both bf16 ----------------
// C_store[col][c_off+row] ; col-stride ldc ; f32 or bf16 out.
template <bool HSW, bool ROWB, bool COLB, bool OUTBF>
__global__ __launch_bounds__(256, 2) void gemm_mfma_k(
    const __bf16* __restrict__ A, long sAb,
    const __bf16* __restrict__ Bt, long sBb,
    void* __restrict__ Cm, long sCb,
    const float* __restrict__ bias,
    int K, int ldc, int c_off) {
  __shared__ __bf16 As[128 * 64];
  __shared__ __bf16 Bs[128 * 64];
  const int tid = threadIdx.x;
  const int lane = tid & 63, wid = tid >> 6;
  const int wm = (wid >> 1) * 64, wn = (wid & 1) * 64;
  const int lr = lane & 15, lg = lane >> 4;
  const int bm = blockIdx.x * 128, bn = blockIdx.y * 128, bz = blockIdx.z;
  const __bf16* Ab = A + (size_t)bz * sAb;
  const __bf16* Bb = Bt + (size_t)bz * sBb;

  f32x4 acc[4][4] = {};

  const int srow = tid >> 3;          // 0..31
  const int schunk = (tid & 7) * 8;   // bf16 elem offset within row

  for (int k0 = 0; k0 < K; k0 += 64) {
#pragma unroll
    for (int p = 0; p < 4; ++p) {
      int row = srow + p * 32;
      int sw = schunk ^ ((row & 7) << 3);   // 16B XOR swizzle (T2)
      *(bf16x8*)&As[row * 64 + sw] = *(const bf16x8*)&Ab[(size_t)(bm + row) * K + k0 + schunk];
      *(bf16x8*)&Bs[row * 64 + sw] = *(const bf16x8*)&Bb[(size_t)(bn + row) * K + k0 + schunk];
    }
    __syncthreads();
#pragma unroll
    for (int kk = 0; kk < 64; kk += 32) {
      bf16x8 af[4], bfv[4];
#pragma unroll
      for (int f = 0; f < 4; ++f) {
        int ar = wm + f * 16 + lr;
        af[f] = *(const bf16x8*)&As[ar * 64 + ((kk + lg * 8) ^ ((ar & 7) << 3))];
        int br = wn + f * 16 + lr;
        bfv[f] = *(const bf16x8*)&Bs[br * 64 + ((kk + lg * 8) ^ ((br & 7) << 3))];
      }
#pragma unroll
      for (int i = 0; i < 4; ++i)
#pragma unroll
        for (int j = 0; j < 4; ++j)
          acc[i][j] = __builtin_amdgcn_mfma_f32_16x16x32_bf16(af[i], bfv[j], acc[i][j], 0, 0, 0);
    }
    __syncthreads();
  }

  // epilogue: D[row][col]: col = lane&15 (+16j), row = (lane>>4)*4+r (+16i). store transposed.
#pragma unroll
  for (int i = 0; i < 4; ++i) {
    int row0 = bm + wm + i * 16 + lg * 4;
    float rb0 = 0.f, rb1 = 0.f, rb2 = 0.f, rb3 = 0.f;
    if (ROWB) { rb0 = bias[row0]; rb1 = bias[row0 + 1]; rb2 = bias[row0 + 2]; rb3 = bias[row0 + 3]; }
#pragma unroll
    for (int j = 0; j < 4; ++j) {
      int col = bn + wn + j * 16 + lr;
      float cbv = COLB ? bias[col] : 0.f;
      float v[4] = {acc[i][j][0] + rb0 + cbv, acc[i][j][1] + rb1 + cbv,
                    acc[i][j][2] + rb2 + cbv, acc[i][j][3] + rb3 + cbv};
      if (HSW) {
#pragma unroll
        for (int r = 0; r < 4; ++r) {
          float u = fminf(fmaxf(v[r] + 3.f, 0.f), 6.f);
          v[r] = v[r] * u * (1.f / 6.f);
        }
      }
      if (OUTBF) {
        __bf16* C = (__bf16*)Cm + (size_t)bz * sCb;
        bf16x4 o;
        o[0] = (__bf16)v[0]; o[1] = (__bf16)v[1]; o[2] = (__bf16)v[2]; o[3] = (__bf16)v[3];
        *(bf16x4*)&C[(size_t)col * ldc + c_off + row0] = o;
      } else {
        float* C = (float*)Cm + (size_t)bz * sCb;
        *(float4*)&C[(size_t)col * ldc + c_off + row0] =
            make_float4(v[0], v[1], v[2], v[3]);
      }
    }
  }
}

extern "C" void kernel_launch(void* const* d_in, const int* in_sizes, int n_in,
                              void* d_out, int out_size, void* d_ws, size_t ws_size,
                              hipStream_t stream) {
  const float* x  = (const float*)d_in[0];
  const float* g  = (const float*)d_in[1];
  const float* be = (const float*)d_in[2];
  const float* w1 = (const float*)d_in[3];
  const float* b1 = (const float*)d_in[4];
  const float* w2 = (const float*)d_in[5];
  const float* b2 = (const float*)d_in[6];
  const float* cw = (const float*)d_in[7];
  const float* cb = (const float*)d_in[8];
  const float* w3 = (const float*)d_in[9];
  const float* b3 = (const float*)d_in[10];
  const float* w4 = (const float*)d_in[11];
  const float* b4 = (const float*)d_in[12];
  float* out = (float*)d_out;

  char* ws = (char*)d_ws;
  float*  stats = (float*)(ws);                      // 512 B
  float*  part  = (float*)(ws + 4096);               // 2 KB
  __bf16* w1b   = (__bf16*)(ws + (1 << 20));         // 512 KB
  __bf16* w2b   = (__bf16*)(ws + (1 << 20) + 524288);
  __bf16* w3b   = (__bf16*)(ws + (2 << 20));         // 128 KB
  __bf16* w4b   = (__bf16*)(ws + (2 << 20) + 131072);
  __bf16* WtT   = (__bf16*)(ws + (3 << 20));         // 1 MB   [512][1024]
  __bf16* xbf   = (__bf16*)(ws + ((size_t)4 << 20));   // 32 MB [B][256][1024]
  __bf16* XnT   = (__bf16*)(ws + ((size_t)36 << 20));  // 32 MB [B][512][512]
  __bf16* Y1T   = (__bf16*)(ws + ((size_t)68 << 20));  // 32 MB [B][512][512]
  __bf16* Z1T   = (__bf16*)(ws + ((size_t)100 << 20)); // 16 MB [B][512][256]
  __bf16* Z3T   = (__bf16*)(ws + ((size_t)116 << 20)); // 16 MB -> 132 MB total

  stats_partial_k<<<256, 256, 0, stream>>>(x, part);
  stats_final_k<<<1, 64, 0, stream>>>(part, stats);
  norm_trans_k<<<dim3(16, 16, NB), dim3(32, 8), 0, stream>>>(x, g, be, stats, XnT, xbf);
  wmask_k<<<1024, 256, 0, stream>>>(w1, w1b, 9);
  wmask_k<<<1024, 256, 0, stream>>>(w2, w2b, 9);
  wmask_k<<<256, 256, 0, stream>>>(w3, w3b, 8);
  wmask_k<<<256, 256, 0, stream>>>(w4, w4b, 8);
  wtprep_k<<<2048, 256, 0, stream>>>(cw, WtT);

  // GEMM1: Y1T = hsw(tril(w1)@Xn + b1)^T          M=512 N=512 K=512
  gemm_mfma_k<true, true, false, true><<<dim3(4, 4, NB), 256, 0, stream>>>(
      w1b, 0, XnT, 262144, Y1T, 262144, b1, 512, 512, 0);
  // GEMM2: out[:, :, 0:512] = (tril(w2)@Y1 + b2)^T   f32
  gemm_mfma_k<false, true, false, false><<<dim3(4, 4, NB), 256, 0, stream>>>(
      w2b, 0, Y1T, 262144, out, 393216, b2, 512, 768, 0);
  // GEMM3 (conv): Z1T = (xr@Wt + cb)^T            M=256 N=512 K=1024
  gemm_mfma_k<false, false, true, true><<<dim3(2, 4, NB), 256, 0, stream>>>(
      xbf, 262144, WtT, 0, Z1T, 131072, cb, 1024, 256, 0);
  // GEMM4: Z3T = hsw(tril(w3)@Z1 + b3)^T          M=256 N=512 K=256
  gemm_mfma_k<true, true, false, true><<<dim3(2, 4, NB), 256, 0, stream>>>(
      w3b, 0, Z1T, 131072, Z3T, 131072, b3, 256, 256, 0);
  // GEMM5: out[:, :, 512:768] = (tril(w4)@Z3 + b4)^T  f32
  gemm_mfma_k<true && false, true, false, false><<<dim3(2, 4, NB), 256, 0, stream>>>(
      w4b, 0, Z3T, 131072, out, 393216, b4, 256, 768, 512);
}

// Round 3
// 161.856 us; speedup vs baseline: 4.8434x; 1.1018x over previous
//
#include <hip/hip_runtime.h>
#include <hip/hip_bf16.h>

// MultiScaleTimeMixer: B=64, T=512, C=512, T2=256
// bf16 MFMA pipeline, all intermediates stored TRANSPOSED ([N x K] for next GEMM).
// R3: global_load_lds staging (linear LDS dest + pre-swizzled global source,
//     swizzled read — rule #21), fused weight prep, vectorized norm_trans.

#define NB 64

typedef __bf16 bf16x8 __attribute__((ext_vector_type(8)));
typedef __bf16 bf16x4 __attribute__((ext_vector_type(4)));
typedef float f32x4 __attribute__((ext_vector_type(4)));

#define AS_GLOBAL __attribute__((address_space(1)))
#define AS_LDS    __attribute__((address_space(3)))

// ---------------- per-batch mean/var ----------------
__global__ void stats_partial_k(const float* __restrict__ x, float* __restrict__ part) {
  int bb = blockIdx.x;  // 256 = 4 per batch
  int b = bb >> 2, q = bb & 3;
  const float4* xb = (const float4*)(x + (size_t)b * 262144 + (size_t)q * 65536);
  float s = 0.f, ss = 0.f;
  for (int it = 0; it < 64; ++it) {
    float4 v = xb[threadIdx.x + 256 * it];
    s += (v.x + v.y) + (v.z + v.w);
    ss += (v.x * v.x + v.y * v.y) + (v.z * v.z + v.w * v.w);
  }
  __shared__ float ls[256], lss[256];
  ls[threadIdx.x] = s; lss[threadIdx.x] = ss;
  __syncthreads();
  for (int off = 128; off > 0; off >>= 1) {
    if (threadIdx.x < off) {
      ls[threadIdx.x] += ls[threadIdx.x + off];
      lss[threadIdx.x] += lss[threadIdx.x + off];
    }
    __syncthreads();
  }
  if (threadIdx.x == 0) { part[bb * 2] = ls[0]; part[bb * 2 + 1] = lss[0]; }
}

__global__ void stats_final_k(const float* __restrict__ part, float* __restrict__ stats) {
  int b = threadIdx.x;
  if (b < NB) {
    float s = 0.f, ss = 0.f;
    for (int q = 0; q < 4; ++q) { s += part[(b * 4 + q) * 2]; ss += part[(b * 4 + q) * 2 + 1]; }
    float mean = s * (1.f / 262144.f);
    float var = ss * (1.f / 262144.f) - mean * mean;
    stats[b * 2] = mean;
    stats[b * 2 + 1] = rsqrtf(var + 1e-5f);
  }
}

// ---- normalize+transpose: XnT[b][c][t] (bf16) + straight bf16 cast xbf[b][t][c] ----
// 64x64 tile, 256 threads. float4 loads, bf16x8/bf16x4 stores.
__global__ __launch_bounds__(256) void norm_trans_k(
    const float* __restrict__ x, const float* __restrict__ g,
    const float* __restrict__ be, const float* __restrict__ stats,
    __bf16* __restrict__ XnT, __bf16* __restrict__ xbf) {
  __shared__ float ls[64][65];   // pad 65: phase-2 col reads 2-way conflict only
  int b = blockIdx.z;
  int bc = blockIdx.x * 64;  // c tile
  int bt = blockIdx.y * 64;  // t tile
  int tid = threadIdx.x;
  float mean = stats[b * 2], istd = stats[b * 2 + 1];
  const float* xb = x + (size_t)b * 262144;
  __bf16* xo = xbf + (size_t)b * 262144;
  int r0 = tid >> 4;          // 0..15
  int c4 = (tid & 15) * 4;
#pragma unroll
  for (int p = 0; p < 4; ++p) {
    int t = p * 16 + r0;
    float4 v = *(const float4*)&xb[(size_t)(bt + t) * 512 + bc + c4];
    ls[t][c4] = v.x; ls[t][c4 + 1] = v.y; ls[t][c4 + 2] = v.z; ls[t][c4 + 3] = v.w;
    bf16x4 o;
    o[0] = (__bf16)v.x; o[1] = (__bf16)v.y; o[2] = (__bf16)v.z; o[3] = (__bf16)v.w;
    *(bf16x4*)&xo[(size_t)(bt + t) * 512 + bc + c4] = o;
  }
  __syncthreads();
  int cr = tid >> 3;          // 0..31
  int t0 = (tid & 7) * 8;
  __bf16* xnb = XnT + (size_t)b * 262144;
#pragma unroll
  for (int p = 0; p < 2; ++p) {
    int cg = bc + p * 32 + cr;
    int cl = p * 32 + cr;
    float4 g0 = *(const float4*)&g[(size_t)cg * 512 + bt + t0];
    float4 g1 = *(const float4*)&g[(size_t)cg * 512 + bt + t0 + 4];
    float4 e0 = *(const float4*)&be[(size_t)cg * 512 + bt + t0];
    float4 e1 = *(const float4*)&be[(size_t)cg * 512 + bt + t0 + 4];
    float gv[8] = {g0.x, g0.y, g0.z, g0.w, g1.x, g1.y, g1.z, g1.w};
    float ev[8] = {e0.x, e0.y, e0.z, e0.w, e1.x, e1.y, e1.z, e1.w};
    bf16x8 o;
#pragma unroll
    for (int j = 0; j < 8; ++j) {
      float xh = (ls[t0 + j][cl] - mean) * istd;
      o[j] = (__bf16)(xh * gv[j] + ev[j]);
    }
    *(bf16x8*)&xnb[(size_t)cg * 512 + bt + t0] = o;
  }
}

// ---- fused weight prep: tril-mask + bf16 for w1..w4, conv-weight reindex ----
__global__ void prep_w_k(const float* __restrict__ w1, const float* __restrict__ w2,
                         const float* __restrict__ w3, const float* __restrict__ w4,
                         const float* __restrict__ cw,
                         __bf16* __restrict__ w1b, __bf16* __restrict__ w2b,
                         __bf16* __restrict__ w3b, __bf16* __restrict__ w4b,
                         __bf16* __restrict__ WtT) {
  int idx = blockIdx.x * 256 + threadIdx.x;
  if (idx < 262144) { int i = idx >> 9, j = idx & 511; w1b[idx] = (__bf16)(j <= i ? w1[idx] : 0.f); return; }
  idx -= 262144;
  if (idx < 262144) { int i = idx >> 9, j = idx & 511; w2b[idx] = (__bf16)(j <= i ? w2[idx] : 0.f); return; }
  idx -= 262144;
  if (idx < 65536) { int i = idx >> 8, j = idx & 255; w3b[idx] = (__bf16)(j <= i ? w3[idx] : 0.f); return; }
  idx -= 65536;
  if (idx < 65536) { int i = idx >> 8, j = idx & 255; w4b[idx] = (__bf16)(j <= i ? w4[idx] : 0.f); return; }
  idx -= 65536;
  // WtT[o][k*512+i] = cw[o][i*2+k]   (B^T layout [512][1024])
  int o = idx >> 10, r = idx & 1023;
  int i = r & 511, k = r >> 9;
  WtT[idx] = (__bf16)cw[(size_t)o * 1024 + i * 2 + k];
}

// ---------------- MFMA GEMM: A [MxK] rm, Bt [NxK] rm (bf16); D^T store ----------------
// LDS layout: row r (128B), 16B-chunk s holds global chunk s ^ (r&7).
// gload_lds: linear dest (elem = tid*8 within tile-quarter), source chunk pre-swizzled.
template <bool HSW, bool ROWB, bool COLB, bool OUTBF>
__global__ __launch_bounds__(256, 2) void gemm_mfma_k(
    const __bf16* __restrict__ A, long sAb,
    const __bf16* __restrict__ Bt, long sBb,
    void* __restrict__ Cm, long sCb,
    const float* __restrict__ bias,
    int K, int ldc, int c_off) {
  __shared__ __align__(16) __bf16 As[128 * 64];
  __shared__ __align__(16) __bf16 Bs[128 * 64];
  const int tid = threadIdx.x;
  const int lane = tid & 63, wid = tid >> 6;
  const int wm = (wid >> 1) * 64, wn = (wid & 1) * 64;
  const int lr = lane & 15, lg = lane >> 4;
  const int bm = blockIdx.x * 128, bn = blockIdx.y * 128, bz = blockIdx.z;

  const int srg = lane >> 3;                  // row within 8-row group == (row&7)
  const int ssrc = ((lane & 7) ^ srg) << 3;   // pre-swizzled source chunk (elems)

  const __bf16* gA[4];
  const __bf16* gB[4];
#pragma unroll
  for (int p = 0; p < 4; ++p) {
    int row = p * 32 + wid * 8 + srg;
    gA[p] = A + (size_t)bz * sAb + (size_t)(bm + row) * K + ssrc;
    gB[p] = Bt + (size_t)bz * sBb + (size_t)(bn + row) * K + ssrc;
  }

  f32x4 acc[4][4] = {};

  for (int k0 = 0; k0 < K; k0 += 64) {
#pragma unroll
    for (int p = 0; p < 4; ++p) {
      __builtin_amdgcn_global_load_lds(
          (const AS_GLOBAL void*)gA[p],
          (AS_LDS void*)&As[(p * 32 + wid * 8) * 64], 16, 0, 0);
      __builtin_amdgcn_global_load_lds(
          (const AS_GLOBAL void*)gB[p],
          (AS_LDS void*)&Bs[(p * 32 + wid * 8) * 64], 16, 0, 0);
      gA[p] += 64;
      gB[p] += 64;
    }
    __syncthreads();
#pragma unroll
    for (int kk = 0; kk < 64; kk += 32) {
      bf16x8 af[4], bfv[4];
#pragma unroll
      for (int f = 0; f < 4; ++f) {
        int ar = wm + f * 16 + lr;
        af[f] = *(const bf16x8*)&As[ar * 64 + ((kk + lg * 8) ^ ((ar & 7) << 3))];
        int br = wn + f * 16 + lr;
        bfv[f] = *(const bf16x8*)&Bs[br * 64 + ((kk + lg * 8) ^ ((br & 7) << 3))];
      }
#pragma unroll
      for (int i = 0; i < 4; ++i)
#pragma unroll
        for (int j = 0; j < 4; ++j)
          acc[i][j] = __builtin_amdgcn_mfma_f32_16x16x32_bf16(af[i], bfv[j], acc[i][j], 0, 0, 0);
    }
    __syncthreads();
  }

  // epilogue: D[row][col]: col = lane&15 (+16j), row = (lane>>4)*4+r (+16i). store D^T.
#pragma unroll
  for (int i = 0; i < 4; ++i) {
    int row0 = bm + wm + i * 16 + lg * 4;
    float rb0 = 0.f, rb1 = 0.f, rb2 = 0.f, rb3 = 0.f;
    if (ROWB) { rb0 = bias[row0]; rb1 = bias[row0 + 1]; rb2 = bias[row0 + 2]; rb3 = bias[row0 + 3]; }
#pragma unroll
    for (int j = 0; j < 4; ++j) {
      int col = bn + wn + j * 16 + lr;
      float cbv = COLB ? bias[col] : 0.f;
      float v[4] = {acc[i][j][0] + rb0 + cbv, acc[i][j][1] + rb1 + cbv,
                    acc[i][j][2] + rb2 + cbv, acc[i][j][3] + rb3 + cbv};
      if (HSW) {
#pragma unroll
        for (int r = 0; r < 4; ++r) {
          float u = fminf(fmaxf(v[r] + 3.f, 0.f), 6.f);
          v[r] = v[r] * u * (1.f / 6.f);
        }
      }
      if (OUTBF) {
        __bf16* C = (__bf16*)Cm + (size_t)bz * sCb;
        bf16x4 o;
        o[0] = (__bf16)v[0]; o[1] = (__bf16)v[1]; o[2] = (__bf16)v[2]; o[3] = (__bf16)v[3];
        *(bf16x4*)&C[(size_t)col * ldc + c_off + row0] = o;
      } else {
        float* C = (float*)Cm + (size_t)bz * sCb;
        *(float4*)&C[(size_t)col * ldc + c_off + row0] =
            make_float4(v[0], v[1], v[2], v[3]);
      }
    }
  }
}

extern "C" void kernel_launch(void* const* d_in, const int* in_sizes, int n_in,
                              void* d_out, int out_size, void* d_ws, size_t ws_size,
                              hipStream_t stream) {
  const float* x  = (const float*)d_in[0];
  const float* g  = (const float*)d_in[1];
  const float* be = (const float*)d_in[2];
  const float* w1 = (const float*)d_in[3];
  const float* b1 = (const float*)d_in[4];
  const float* w2 = (const float*)d_in[5];
  const float* b2 = (const float*)d_in[6];
  const float* cw = (const float*)d_in[7];
  const float* cb = (const float*)d_in[8];
  const float* w3 = (const float*)d_in[9];
  const float* b3 = (const float*)d_in[10];
  const float* w4 = (const float*)d_in[11];
  const float* b4 = (const float*)d_in[12];
  float* out = (float*)d_out;

  char* ws = (char*)d_ws;
  float*  stats = (float*)(ws);                        // 512 B
  float*  part  = (float*)(ws + 4096);                 // 2 KB
  __bf16* w1b   = (__bf16*)(ws + (1 << 20));           // 512 KB
  __bf16* w2b   = (__bf16*)(ws + (1 << 20) + 524288);
  __bf16* w3b   = (__bf16*)(ws + (2 << 20));           // 128 KB
  __bf16* w4b   = (__bf16*)(ws + (2 << 20) + 131072);
  __bf16* WtT   = (__bf16*)(ws + (3 << 20));           // 1 MB   [512][1024]
  __bf16* xbf   = (__bf16*)(ws + ((size_t)4 << 20));   // 32 MB [B][256][1024]
  __bf16* XnT   = (__bf16*)(ws + ((size_t)36 << 20));  // 32 MB [B][512][512]
  __bf16* Y1T   = (__bf16*)(ws + ((size_t)68 << 20));  // 32 MB [B][512][512]
  __bf16* Z1T   = (__bf16*)(ws + ((size_t)100 << 20)); // 16 MB [B][512][256]
  __bf16* Z3T   = (__bf16*)(ws + ((size_t)116 << 20)); // 16 MB -> 132 MB total

  stats_partial_k<<<256, 256, 0, stream>>>(x, part);
  stats_final_k<<<1, 64, 0, stream>>>(part, stats);
  norm_trans_k<<<dim3(8, 8, NB), 256, 0, stream>>>(x, g, be, stats, XnT, xbf);
  prep_w_k<<<4608, 256, 0, stream>>>(w1, w2, w3, w4, cw, w1b, w2b, w3b, w4b, WtT);

  // GEMM1: Y1T = hsw(tril(w1)@Xn + b1)^T          M=512 N=512 K=512
  gemm_mfma_k<true, true, false, true><<<dim3(4, 4, NB), 256, 0, stream>>>(
      w1b, 0, XnT, 262144, Y1T, 262144, b1, 512, 512, 0);
  // GEMM2: out[:, :, 0:512] = (tril(w2)@Y1 + b2)^T   f32
  gemm_mfma_k<false, true, false, false><<<dim3(4, 4, NB), 256, 0, stream>>>(
      w2b, 0, Y1T, 262144, out, 393216, b2, 512, 768, 0);
  // GEMM3 (conv): Z1T = (xr@Wt + cb)^T            M=256 N=512 K=1024
  gemm_mfma_k<false, false, true, true><<<dim3(2, 4, NB), 256, 0, stream>>>(
      xbf, 262144, WtT, 0, Z1T, 131072, cb, 1024, 256, 0);
  // GEMM4: Z3T = hsw(tril(w3)@Z1 + b3)^T          M=256 N=512 K=256
  gemm_mfma_k<true, true, false, true><<<dim3(2, 4, NB), 256, 0, stream>>>(
      w3b, 0, Z1T, 131072, Z3T, 131072, b3, 256, 256, 0);
  // GEMM5: out[:, :, 512:768] = (tril(w4)@Z3 + b4)^T  f32
  gemm_mfma_k<false, true, false, false><<<dim3(2, 4, NB), 256, 0, stream>>>(
      w4b, 0, Z3T, 131072, out, 393216, b4, 256, 768, 512);
}

// Round 4
// 151.576 us; speedup vs baseline: 5.1719x; 1.0678x over previous
//
#include <hip/hip_runtime.h>
#include <hip/hip_bf16.h>

// MultiScaleTimeMixer: B=64, T=512, C=512, T2=256
// bf16 MFMA pipeline, intermediates stored TRANSPOSED ([N x K] for next GEMM).
// R4: 3 blocks/CU, XCD-chunked block swizzle (T1), fused stats+weight-prep.

#define NB 64

typedef __bf16 bf16x8 __attribute__((ext_vector_type(8)));
typedef __bf16 bf16x4 __attribute__((ext_vector_type(4)));
typedef float f32x4 __attribute__((ext_vector_type(4)));

#define AS_GLOBAL __attribute__((address_space(1)))
#define AS_LDS    __attribute__((address_space(3)))

// ---- fused: per-batch partial stats (blocks 0..255) + weight prep (blocks 256+) ----
__global__ void pre1_k(const float* __restrict__ x, float* __restrict__ part,
                       const float* __restrict__ w1, const float* __restrict__ w2,
                       const float* __restrict__ w3, const float* __restrict__ w4,
                       const float* __restrict__ cw,
                       __bf16* __restrict__ w1b, __bf16* __restrict__ w2b,
                       __bf16* __restrict__ w3b, __bf16* __restrict__ w4b,
                       __bf16* __restrict__ WtT) {
  if (blockIdx.x < 256) {
    int bb = blockIdx.x;  // 4 per batch
    int b = bb >> 2, q = bb & 3;
    const float4* xb = (const float4*)(x + (size_t)b * 262144 + (size_t)q * 65536);
    float s = 0.f, ss = 0.f;
    for (int it = 0; it < 64; ++it) {
      float4 v = xb[threadIdx.x + 256 * it];
      s += (v.x + v.y) + (v.z + v.w);
      ss += (v.x * v.x + v.y * v.y) + (v.z * v.z + v.w * v.w);
    }
    __shared__ float ls[256], lss[256];
    ls[threadIdx.x] = s; lss[threadIdx.x] = ss;
    __syncthreads();
    for (int off = 128; off > 0; off >>= 1) {
      if (threadIdx.x < off) {
        ls[threadIdx.x] += ls[threadIdx.x + off];
        lss[threadIdx.x] += lss[threadIdx.x + off];
      }
      __syncthreads();
    }
    if (threadIdx.x == 0) { part[bb * 2] = ls[0]; part[bb * 2 + 1] = lss[0]; }
    return;
  }
  int idx = (blockIdx.x - 256) * 256 + threadIdx.x;
  if (idx < 262144) { int i = idx >> 9, j = idx & 511; w1b[idx] = (__bf16)(j <= i ? w1[idx] : 0.f); return; }
  idx -= 262144;
  if (idx < 262144) { int i = idx >> 9, j = idx & 511; w2b[idx] = (__bf16)(j <= i ? w2[idx] : 0.f); return; }
  idx -= 262144;
  if (idx < 65536) { int i = idx >> 8, j = idx & 255; w3b[idx] = (__bf16)(j <= i ? w3[idx] : 0.f); return; }
  idx -= 65536;
  if (idx < 65536) { int i = idx >> 8, j = idx & 255; w4b[idx] = (__bf16)(j <= i ? w4[idx] : 0.f); return; }
  idx -= 65536;
  // WtT[o][k*512+i] = cw[o][i*2+k]   (B^T layout [512][1024])
  int o = idx >> 10, r = idx & 1023;
  int i = r & 511, k = r >> 9;
  WtT[idx] = (__bf16)cw[(size_t)o * 1024 + i * 2 + k];
}

__global__ void stats_final_k(const float* __restrict__ part, float* __restrict__ stats) {
  int b = threadIdx.x;
  if (b < NB) {
    float s = 0.f, ss = 0.f;
    for (int q = 0; q < 4; ++q) { s += part[(b * 4 + q) * 2]; ss += part[(b * 4 + q) * 2 + 1]; }
    float mean = s * (1.f / 262144.f);
    float var = ss * (1.f / 262144.f) - mean * mean;
    stats[b * 2] = mean;
    stats[b * 2 + 1] = rsqrtf(var + 1e-5f);
  }
}

// ---- normalize+transpose: XnT[b][c][t] (bf16) + straight bf16 cast xbf[b][t][c] ----
__global__ __launch_bounds__(256) void norm_trans_k(
    const float* __restrict__ x, const float* __restrict__ g,
    const float* __restrict__ be, const float* __restrict__ stats,
    __bf16* __restrict__ XnT, __bf16* __restrict__ xbf) {
  __shared__ float ls[64][65];
  int b = blockIdx.z;
  int bc = blockIdx.x * 64;  // c tile
  int bt = blockIdx.y * 64;  // t tile
  int tid = threadIdx.x;
  float mean = stats[b * 2], istd = stats[b * 2 + 1];
  const float* xb = x + (size_t)b * 262144;
  __bf16* xo = xbf + (size_t)b * 262144;
  int r0 = tid >> 4;
  int c4 = (tid & 15) * 4;
#pragma unroll
  for (int p = 0; p < 4; ++p) {
    int t = p * 16 + r0;
    float4 v = *(const float4*)&xb[(size_t)(bt + t) * 512 + bc + c4];
    ls[t][c4] = v.x; ls[t][c4 + 1] = v.y; ls[t][c4 + 2] = v.z; ls[t][c4 + 3] = v.w;
    bf16x4 o;
    o[0] = (__bf16)v.x; o[1] = (__bf16)v.y; o[2] = (__bf16)v.z; o[3] = (__bf16)v.w;
    *(bf16x4*)&xo[(size_t)(bt + t) * 512 + bc + c4] = o;
  }
  __syncthreads();
  int cr = tid >> 3;
  int t0 = (tid & 7) * 8;
  __bf16* xnb = XnT + (size_t)b * 262144;
#pragma unroll
  for (int p = 0; p < 2; ++p) {
    int cg = bc + p * 32 + cr;
    int cl = p * 32 + cr;
    float4 g0 = *(const float4*)&g[(size_t)cg * 512 + bt + t0];
    float4 g1 = *(const float4*)&g[(size_t)cg * 512 + bt + t0 + 4];
    float4 e0 = *(const float4*)&be[(size_t)cg * 512 + bt + t0];
    float4 e1 = *(const float4*)&be[(size_t)cg * 512 + bt + t0 + 4];
    float gv[8] = {g0.x, g0.y, g0.z, g0.w, g1.x, g1.y, g1.z, g1.w};
    float ev[8] = {e0.x, e0.y, e0.z, e0.w, e1.x, e1.y, e1.z, e1.w};
    bf16x8 o;
#pragma unroll
    for (int j = 0; j < 8; ++j) {
      float xh = (ls[t0 + j][cl] - mean) * istd;
      o[j] = (__bf16)(xh * gv[j] + ev[j]);
    }
    *(bf16x8*)&xnb[(size_t)cg * 512 + bt + t0] = o;
  }
}

// ---------------- MFMA GEMM: A [MxK] rm, Bt [NxK] rm (bf16); D^T store ----------------
// LDS: row r (128B), 16B-chunk s holds global chunk s ^ (r&7); gload_lds linear dest,
// source pre-swizzled (rule #21). XCD-chunked block swizzle (T1/m204): grid always
// (2^LGX, 4, 64), nwg % 8 == 0.
template <int LGX, bool HSW, bool ROWB, bool COLB, bool OUTBF>
__global__ __launch_bounds__(256, 3) void gemm_mfma_k(
    const __bf16* __restrict__ A, long sAb,
    const __bf16* __restrict__ Bt, long sBb,
    void* __restrict__ Cm, long sCb,
    const float* __restrict__ bias,
    int K, int ldc, int c_off) {
  __shared__ __align__(16) __bf16 As[128 * 64];
  __shared__ __align__(16) __bf16 Bs[128 * 64];
  const int tid = threadIdx.x;
  const int lane = tid & 63, wid = tid >> 6;
  const int wm = (wid >> 1) * 64, wn = (wid & 1) * 64;
  const int lr = lane & 15, lg = lane >> 4;

  // XCD swizzle: consecutive new-ids stay on one XCD chunk -> B/A panel L2 reuse
  const int bid = blockIdx.x + (blockIdx.y << LGX) + (blockIdx.z << (LGX + 2));
  const int nid = ((bid & 7) << (LGX + 5)) | (bid >> 3);
  const int bm = (nid & ((1 << LGX) - 1)) * 128;
  const int bn = ((nid >> LGX) & 3) * 128;
  const int bz = nid >> (LGX + 2);

  const int srg = lane >> 3;                  // row within 8-row group == (row&7)
  const int ssrc = ((lane & 7) ^ srg) << 3;   // pre-swizzled source chunk (elems)

  const __bf16* gA[4];
  const __bf16* gB[4];
#pragma unroll
  for (int p = 0; p < 4; ++p) {
    int row = p * 32 + wid * 8 + srg;
    gA[p] = A + (size_t)bz * sAb + (size_t)(bm + row) * K + ssrc;
    gB[p] = Bt + (size_t)bz * sBb + (size_t)(bn + row) * K + ssrc;
  }

  f32x4 acc[4][4] = {};

  for (int k0 = 0; k0 < K; k0 += 64) {
#pragma unroll
    for (int p = 0; p < 4; ++p) {
      __builtin_amdgcn_global_load_lds(
          (const AS_GLOBAL void*)gA[p],
          (AS_LDS void*)&As[(p * 32 + wid * 8) * 64], 16, 0, 0);
      __builtin_amdgcn_global_load_lds(
          (const AS_GLOBAL void*)gB[p],
          (AS_LDS void*)&Bs[(p * 32 + wid * 8) * 64], 16, 0, 0);
      gA[p] += 64;
      gB[p] += 64;
    }
    __syncthreads();
#pragma unroll
    for (int kk = 0; kk < 64; kk += 32) {
      bf16x8 af[4], bfv[4];
#pragma unroll
      for (int f = 0; f < 4; ++f) {
        int ar = wm + f * 16 + lr;
        af[f] = *(const bf16x8*)&As[ar * 64 + ((kk + lg * 8) ^ ((ar & 7) << 3))];
        int br = wn + f * 16 + lr;
        bfv[f] = *(const bf16x8*)&Bs[br * 64 + ((kk + lg * 8) ^ ((br & 7) << 3))];
      }
#pragma unroll
      for (int i = 0; i < 4; ++i)
#pragma unroll
        for (int j = 0; j < 4; ++j)
          acc[i][j] = __builtin_amdgcn_mfma_f32_16x16x32_bf16(af[i], bfv[j], acc[i][j], 0, 0, 0);
    }
    __syncthreads();
  }

  // epilogue: D[row][col]: col = lane&15 (+16j), row = (lane>>4)*4+r (+16i). store D^T.
#pragma unroll
  for (int i = 0; i < 4; ++i) {
    int row0 = bm + wm + i * 16 + lg * 4;
    float rb0 = 0.f, rb1 = 0.f, rb2 = 0.f, rb3 = 0.f;
    if (ROWB) { rb0 = bias[row0]; rb1 = bias[row0 + 1]; rb2 = bias[row0 + 2]; rb3 = bias[row0 + 3]; }
#pragma unroll
    for (int j = 0; j < 4; ++j) {
      int col = bn + wn + j * 16 + lr;
      float cbv = COLB ? bias[col] : 0.f;
      float v[4] = {acc[i][j][0] + rb0 + cbv, acc[i][j][1] + rb1 + cbv,
                    acc[i][j][2] + rb2 + cbv, acc[i][j][3] + rb3 + cbv};
      if (HSW) {
#pragma unroll
        for (int r = 0; r < 4; ++r) {
          float u = fminf(fmaxf(v[r] + 3.f, 0.f), 6.f);
          v[r] = v[r] * u * (1.f / 6.f);
        }
      }
      if (OUTBF) {
        __bf16* C = (__bf16*)Cm + (size_t)bz * sCb;
        bf16x4 o;
        o[0] = (__bf16)v[0]; o[1] = (__bf16)v[1]; o[2] = (__bf16)v[2]; o[3] = (__bf16)v[3];
        *(bf16x4*)&C[(size_t)col * ldc + c_off + row0] = o;
      } else {
        float* C = (float*)Cm + (size_t)bz * sCb;
        *(float4*)&C[(size_t)col * ldc + c_off + row0] =
            make_float4(v[0], v[1], v[2], v[3]);
      }
    }
  }
}

extern "C" void kernel_launch(void* const* d_in, const int* in_sizes, int n_in,
                              void* d_out, int out_size, void* d_ws, size_t ws_size,
                              hipStream_t stream) {
  const float* x  = (const float*)d_in[0];
  const float* g  = (const float*)d_in[1];
  const float* be = (const float*)d_in[2];
  const float* w1 = (const float*)d_in[3];
  const float* b1 = (const float*)d_in[4];
  const float* w2 = (const float*)d_in[5];
  const float* b2 = (const float*)d_in[6];
  const float* cw = (const float*)d_in[7];
  const float* cb = (const float*)d_in[8];
  const float* w3 = (const float*)d_in[9];
  const float* b3 = (const float*)d_in[10];
  const float* w4 = (const float*)d_in[11];
  const float* b4 = (const float*)d_in[12];
  float* out = (float*)d_out;

  char* ws = (char*)d_ws;
  float*  stats = (float*)(ws);                        // 512 B
  float*  part  = (float*)(ws + 4096);                 // 2 KB
  __bf16* w1b   = (__bf16*)(ws + (1 << 20));           // 512 KB
  __bf16* w2b   = (__bf16*)(ws + (1 << 20) + 524288);
  __bf16* w3b   = (__bf16*)(ws + (2 << 20));           // 128 KB
  __bf16* w4b   = (__bf16*)(ws + (2 << 20) + 131072);
  __bf16* WtT   = (__bf16*)(ws + (3 << 20));           // 1 MB   [512][1024]
  __bf16* xbf   = (__bf16*)(ws + ((size_t)4 << 20));   // 32 MB [B][256][1024]
  __bf16* XnT   = (__bf16*)(ws + ((size_t)36 << 20));  // 32 MB [B][512][512]
  __bf16* Y1T   = (__bf16*)(ws + ((size_t)68 << 20));  // 32 MB [B][512][512]
  __bf16* Z1T   = (__bf16*)(ws + ((size_t)100 << 20)); // 16 MB [B][512][256]
  __bf16* Z3T   = (__bf16*)(ws + ((size_t)116 << 20)); // 16 MB -> 132 MB total

  // stats (256 blocks) + weight prep (4608 blocks) fused
  pre1_k<<<4864, 256, 0, stream>>>(x, part, w1, w2, w3, w4, cw, w1b, w2b, w3b, w4b, WtT);
  stats_final_k<<<1, 64, 0, stream>>>(part, stats);
  norm_trans_k<<<dim3(8, 8, NB), 256, 0, stream>>>(x, g, be, stats, XnT, xbf);

  // GEMM1: Y1T = hsw(tril(w1)@Xn + b1)^T          M=512 N=512 K=512
  gemm_mfma_k<2, true, true, false, true><<<dim3(4, 4, NB), 256, 0, stream>>>(
      w1b, 0, XnT, 262144, Y1T, 262144, b1, 512, 512, 0);
  // GEMM2: out[:, :, 0:512] = (tril(w2)@Y1 + b2)^T   f32
  gemm_mfma_k<2, false, true, false, false><<<dim3(4, 4, NB), 256, 0, stream>>>(
      w2b, 0, Y1T, 262144, out, 393216, b2, 512, 768, 0);
  // GEMM3 (conv): Z1T = (xr@Wt + cb)^T            M=256 N=512 K=1024
  gemm_mfma_k<1, false, false, true, true><<<dim3(2, 4, NB), 256, 0, stream>>>(
      xbf, 262144, WtT, 0, Z1T, 131072, cb, 1024, 256, 0);
  // GEMM4: Z3T = hsw(tril(w3)@Z1 + b3)^T          M=256 N=512 K=256
  gemm_mfma_k<1, true, true, false, true><<<dim3(2, 4, NB), 256, 0, stream>>>(
      w3b, 0, Z1T, 131072, Z3T, 131072, b3, 256, 256, 0);
  // GEMM5: out[:, :, 512:768] = (tril(w4)@Z3 + b4)^T  f32
  gemm_mfma_k<1, false, true, false, false><<<dim3(2, 4, NB), 256, 0, stream>>>(
      w4b, 0, Z3T, 131072, out, 393216, b4, 256, 768, 512);
}

// Round 5
// 132.978 us; speedup vs baseline: 5.8952x; 1.1399x over previous
//
#include <hip/hip_runtime.h>
#include <hip/hip_bf16.h>

// MultiScaleTimeMixer: B=64, T=512, C=512, T2=256
// bf16 MFMA pipeline, intermediates TRANSPOSED ([N x K] for next GEMM).
// R5: 4-launch DAG: pre1(stats+xbf+weights) -> [G3|norm] -> [G1|G4] -> [G2|G5].

#define NB 64

typedef __bf16 bf16x8 __attribute__((ext_vector_type(8)));
typedef __bf16 bf16x4 __attribute__((ext_vector_type(4)));
typedef float f32x4 __attribute__((ext_vector_type(4)));

#define AS_GLOBAL __attribute__((address_space(1)))
#define AS_LDS    __attribute__((address_space(3)))

// ---- fused: per-batch partial stats + xbf cast (blocks 0..255) + weight prep ----
__global__ void pre1_k(const float* __restrict__ x, float* __restrict__ part,
                       __bf16* __restrict__ xbf,
                       const float* __restrict__ w1, const float* __restrict__ w2,
                       const float* __restrict__ w3, const float* __restrict__ w4,
                       const float* __restrict__ cw,
                       __bf16* __restrict__ w1b, __bf16* __restrict__ w2b,
                       __bf16* __restrict__ w3b, __bf16* __restrict__ w4b,
                       __bf16* __restrict__ WtT) {
  if (blockIdx.x < 256) {
    int bb = blockIdx.x;  // 4 per batch
    int b = bb >> 2, q = bb & 3;
    size_t base = (size_t)b * 262144 + (size_t)q * 65536;
    const float4* xb = (const float4*)(x + base);
    bf16x4* xo = (bf16x4*)(xbf + base);
    float s = 0.f, ss = 0.f;
    for (int it = 0; it < 64; ++it) {
      int idx = threadIdx.x + 256 * it;
      float4 v = xb[idx];
      s += (v.x + v.y) + (v.z + v.w);
      ss += (v.x * v.x + v.y * v.y) + (v.z * v.z + v.w * v.w);
      bf16x4 o;
      o[0] = (__bf16)v.x; o[1] = (__bf16)v.y; o[2] = (__bf16)v.z; o[3] = (__bf16)v.w;
      xo[idx] = o;
    }
    __shared__ float ls[256], lss[256];
    ls[threadIdx.x] = s; lss[threadIdx.x] = ss;
    __syncthreads();
    for (int off = 128; off > 0; off >>= 1) {
      if (threadIdx.x < off) {
        ls[threadIdx.x] += ls[threadIdx.x + off];
        lss[threadIdx.x] += lss[threadIdx.x + off];
      }
      __syncthreads();
    }
    if (threadIdx.x == 0) { part[bb * 2] = ls[0]; part[bb * 2 + 1] = lss[0]; }
    return;
  }
  int idx = (blockIdx.x - 256) * 256 + threadIdx.x;
  if (idx < 262144) { int i = idx >> 9, j = idx & 511; w1b[idx] = (__bf16)(j <= i ? w1[idx] : 0.f); return; }
  idx -= 262144;
  if (idx < 262144) { int i = idx >> 9, j = idx & 511; w2b[idx] = (__bf16)(j <= i ? w2[idx] : 0.f); return; }
  idx -= 262144;
  if (idx < 65536) { int i = idx >> 8, j = idx & 255; w3b[idx] = (__bf16)(j <= i ? w3[idx] : 0.f); return; }
  idx -= 65536;
  if (idx < 65536) { int i = idx >> 8, j = idx & 255; w4b[idx] = (__bf16)(j <= i ? w4[idx] : 0.f); return; }
  idx -= 65536;
  // WtT[o][k*512+i] = cw[o][i*2+k]   (B^T layout [512][1024])
  int o = idx >> 10, r = idx & 1023;
  int i = r & 511, k = r >> 9;
  WtT[idx] = (__bf16)cw[(size_t)o * 1024 + i * 2 + k];
}

// ---------------- GEMM body: A [MxK] rm, Bt [NxK] rm (bf16); D^T store ----------------
// LDS: row r (128B), 16B-chunk s holds global chunk s ^ (r&7); gload_lds linear dest,
// source pre-swizzled (rule #21). XCD-chunked swizzle, runtime lgx (nwg%8==0).
template <bool HSW, bool ROWB, bool COLB, bool OUTBF>
__device__ __forceinline__ void gemm_body(
    int bid, int lgx, __bf16* As, __bf16* Bs,
    const __bf16* __restrict__ A, long sAb,
    const __bf16* __restrict__ Bt, long sBb,
    void* __restrict__ Cm, long sCb,
    const float* __restrict__ bias,
    int K, int ldc, int c_off) {
  const int tid = threadIdx.x;
  const int lane = tid & 63, wid = tid >> 6;
  const int wm = (wid >> 1) * 64, wn = (wid & 1) * 64;
  const int lr = lane & 15, lg = lane >> 4;

  const int nid = ((bid & 7) << (lgx + 5)) | (bid >> 3);
  const int bm = (nid & ((1 << lgx) - 1)) * 128;
  const int bn = ((nid >> lgx) & 3) * 128;
  const int bz = nid >> (lgx + 2);

  const int srg = lane >> 3;                  // row within 8-row group == (row&7)
  const int ssrc = ((lane & 7) ^ srg) << 3;   // pre-swizzled source chunk (elems)

  const __bf16* gA[4];
  const __bf16* gB[4];
#pragma unroll
  for (int p = 0; p < 4; ++p) {
    int row = p * 32 + wid * 8 + srg;
    gA[p] = A + (size_t)bz * sAb + (size_t)(bm + row) * K + ssrc;
    gB[p] = Bt + (size_t)bz * sBb + (size_t)(bn + row) * K + ssrc;
  }

  f32x4 acc[4][4] = {};

  for (int k0 = 0; k0 < K; k0 += 64) {
#pragma unroll
    for (int p = 0; p < 4; ++p) {
      __builtin_amdgcn_global_load_lds(
          (const AS_GLOBAL void*)gA[p],
          (AS_LDS void*)&As[(p * 32 + wid * 8) * 64], 16, 0, 0);
      __builtin_amdgcn_global_load_lds(
          (const AS_GLOBAL void*)gB[p],
          (AS_LDS void*)&Bs[(p * 32 + wid * 8) * 64], 16, 0, 0);
      gA[p] += 64;
      gB[p] += 64;
    }
    __syncthreads();
#pragma unroll
    for (int kk = 0; kk < 64; kk += 32) {
      bf16x8 af[4], bfv[4];
#pragma unroll
      for (int f = 0; f < 4; ++f) {
        int ar = wm + f * 16 + lr;
        af[f] = *(const bf16x8*)&As[ar * 64 + ((kk + lg * 8) ^ ((ar & 7) << 3))];
        int br = wn + f * 16 + lr;
        bfv[f] = *(const bf16x8*)&Bs[br * 64 + ((kk + lg * 8) ^ ((br & 7) << 3))];
      }
#pragma unroll
      for (int i = 0; i < 4; ++i)
#pragma unroll
        for (int j = 0; j < 4; ++j)
          acc[i][j] = __builtin_amdgcn_mfma_f32_16x16x32_bf16(af[i], bfv[j], acc[i][j], 0, 0, 0);
    }
    __syncthreads();
  }

  // epilogue: D[row][col]: col = lane&15 (+16j), row = (lane>>4)*4+r (+16i). store D^T.
#pragma unroll
  for (int i = 0; i < 4; ++i) {
    int row0 = bm + wm + i * 16 + lg * 4;
    float rb0 = 0.f, rb1 = 0.f, rb2 = 0.f, rb3 = 0.f;
    if (ROWB) { rb0 = bias[row0]; rb1 = bias[row0 + 1]; rb2 = bias[row0 + 2]; rb3 = bias[row0 + 3]; }
#pragma unroll
    for (int j = 0; j < 4; ++j) {
      int col = bn + wn + j * 16 + lr;
      float cbv = COLB ? bias[col] : 0.f;
      float v[4] = {acc[i][j][0] + rb0 + cbv, acc[i][j][1] + rb1 + cbv,
                    acc[i][j][2] + rb2 + cbv, acc[i][j][3] + rb3 + cbv};
      if (HSW) {
#pragma unroll
        for (int r = 0; r < 4; ++r) {
          float u = fminf(fmaxf(v[r] + 3.f, 0.f), 6.f);
          v[r] = v[r] * u * (1.f / 6.f);
        }
      }
      if (OUTBF) {
        __bf16* C = (__bf16*)Cm + (size_t)bz * sCb;
        bf16x4 o;
        o[0] = (__bf16)v[0]; o[1] = (__bf16)v[1]; o[2] = (__bf16)v[2]; o[3] = (__bf16)v[3];
        *(bf16x4*)&C[(size_t)col * ldc + c_off + row0] = o;
      } else {
        float* C = (float*)Cm + (size_t)bz * sCb;
        *(float4*)&C[(size_t)col * ldc + c_off + row0] =
            make_float4(v[0], v[1], v[2], v[3]);
      }
    }
  }
}

// ---- norm body: XnT[b][c][t] = bf16(((x-mean)*istd)*g + be), 64x64 tile ----
__device__ __forceinline__ void norm_body(
    int bid, char* smem,
    const float* __restrict__ x, const float* __restrict__ g,
    const float* __restrict__ be, const float* __restrict__ part,
    __bf16* __restrict__ XnT) {
  float (*ls)[65] = (float(*)[65])smem;
  int b = bid >> 6;
  int r = bid & 63;
  int bc = (r & 7) * 64;   // c tile
  int bt = (r >> 3) * 64;  // t tile
  int tid = threadIdx.x;
  // per-block stats from partials (broadcast loads)
  float s = 0.f, ss = 0.f;
#pragma unroll
  for (int q = 0; q < 4; ++q) { s += part[(b * 4 + q) * 2]; ss += part[(b * 4 + q) * 2 + 1]; }
  float mean = s * (1.f / 262144.f);
  float istd = rsqrtf(ss * (1.f / 262144.f) - mean * mean + 1e-5f);

  const float* xb = x + (size_t)b * 262144;
  int r0 = tid >> 4;
  int c4 = (tid & 15) * 4;
#pragma unroll
  for (int p = 0; p < 4; ++p) {
    int t = p * 16 + r0;
    float4 v = *(const float4*)&xb[(size_t)(bt + t) * 512 + bc + c4];
    ls[t][c4] = v.x; ls[t][c4 + 1] = v.y; ls[t][c4 + 2] = v.z; ls[t][c4 + 3] = v.w;
  }
  __syncthreads();
  int cr = tid >> 3;
  int t0 = (tid & 7) * 8;
  __bf16* xnb = XnT + (size_t)b * 262144;
#pragma unroll
  for (int p = 0; p < 2; ++p) {
    int cg = bc + p * 32 + cr;
    int cl = p * 32 + cr;
    float4 g0 = *(const float4*)&g[(size_t)cg * 512 + bt + t0];
    float4 g1 = *(const float4*)&g[(size_t)cg * 512 + bt + t0 + 4];
    float4 e0 = *(const float4*)&be[(size_t)cg * 512 + bt + t0];
    float4 e1 = *(const float4*)&be[(size_t)cg * 512 + bt + t0 + 4];
    float gv[8] = {g0.x, g0.y, g0.z, g0.w, g1.x, g1.y, g1.z, g1.w};
    float ev[8] = {e0.x, e0.y, e0.z, e0.w, e1.x, e1.y, e1.z, e1.w};
    bf16x8 o;
#pragma unroll
    for (int j = 0; j < 8; ++j) {
      float xh = (ls[t0 + j][cl] - mean) * istd;
      o[j] = (__bf16)(xh * gv[j] + ev[j]);
    }
    *(bf16x8*)&xnb[(size_t)cg * 512 + bt + t0] = o;
  }
}

// ---- L2: G3 (conv-as-GEMM, blocks 0..511) | norm (blocks 512..4607) ----
__global__ __launch_bounds__(256, 3) void fused_g3_norm_k(
    const __bf16* __restrict__ xbf, const __bf16* __restrict__ WtT,
    __bf16* __restrict__ Z1T, const float* __restrict__ cb,
    const float* __restrict__ x, const float* __restrict__ g,
    const float* __restrict__ be, const float* __restrict__ part,
    __bf16* __restrict__ XnT) {
  __shared__ __align__(16) char smem[33280];
  __bf16* As = (__bf16*)smem;
  __bf16* Bs = (__bf16*)(smem + 16384);
  int bid = blockIdx.x;
  if (bid < 512) {
    gemm_body<false, false, true, true>(bid, 1, As, Bs,
        xbf, 262144, WtT, 0, Z1T, 131072, cb, 1024, 256, 0);
  } else {
    norm_body(bid - 512, smem, x, g, be, part, XnT);
  }
}

// ---- L3: G1 (blocks 0..1023) | G4 (blocks 1024..1535) ----
__global__ __launch_bounds__(256, 3) void fused_g1_g4_k(
    const __bf16* __restrict__ w1b, const __bf16* __restrict__ XnT,
    __bf16* __restrict__ Y1T, const float* __restrict__ b1,
    const __bf16* __restrict__ w3b, const __bf16* __restrict__ Z1T,
    __bf16* __restrict__ Z3T, const float* __restrict__ b3) {
  __shared__ __align__(16) char smem[32768];
  __bf16* As = (__bf16*)smem;
  __bf16* Bs = (__bf16*)(smem + 16384);
  int bid = blockIdx.x;
  if (bid < 1024)
    gemm_body<true, true, false, true>(bid, 2, As, Bs,
        w1b, 0, XnT, 262144, Y1T, 262144, b1, 512, 512, 0);
  else
    gemm_body<true, true, false, true>(bid - 1024, 1, As, Bs,
        w3b, 0, Z1T, 131072, Z3T, 131072, b3, 256, 256, 0);
}

// ---- L4: G2 (blocks 0..1023) | G5 (blocks 1024..1535) ----
__global__ __launch_bounds__(256, 3) void fused_g2_g5_k(
    const __bf16* __restrict__ w2b, const __bf16* __restrict__ Y1T,
    float* __restrict__ out, const float* __restrict__ b2,
    const __bf16* __restrict__ w4b, const __bf16* __restrict__ Z3T,
    const float* __restrict__ b4) {
  __shared__ __align__(16) char smem[32768];
  __bf16* As = (__bf16*)smem;
  __bf16* Bs = (__bf16*)(smem + 16384);
  int bid = blockIdx.x;
  if (bid < 1024)
    gemm_body<false, true, false, false>(bid, 2, As, Bs,
        w2b, 0, Y1T, 262144, out, 393216, b2, 512, 768, 0);
  else
    gemm_body<false, true, false, false>(bid - 1024, 1, As, Bs,
        w4b, 0, Z3T, 131072, out, 393216, b4, 256, 768, 512);
}

extern "C" void kernel_launch(void* const* d_in, const int* in_sizes, int n_in,
                              void* d_out, int out_size, void* d_ws, size_t ws_size,
                              hipStream_t stream) {
  const float* x  = (const float*)d_in[0];
  const float* g  = (const float*)d_in[1];
  const float* be = (const float*)d_in[2];
  const float* w1 = (const float*)d_in[3];
  const float* b1 = (const float*)d_in[4];
  const float* w2 = (const float*)d_in[5];
  const float* b2 = (const float*)d_in[6];
  const float* cw = (const float*)d_in[7];
  const float* cb = (const float*)d_in[8];
  const float* w3 = (const float*)d_in[9];
  const float* b3 = (const float*)d_in[10];
  const float* w4 = (const float*)d_in[11];
  const float* b4 = (const float*)d_in[12];
  float* out = (float*)d_out;

  char* ws = (char*)d_ws;
  float*  part  = (float*)(ws + 4096);                 // 2 KB
  __bf16* w1b   = (__bf16*)(ws + (1 << 20));           // 512 KB
  __bf16* w2b   = (__bf16*)(ws + (1 << 20) + 524288);
  __bf16* w3b   = (__bf16*)(ws + (2 << 20));           // 128 KB
  __bf16* w4b   = (__bf16*)(ws + (2 << 20) + 131072);
  __bf16* WtT   = (__bf16*)(ws + (3 << 20));           // 1 MB   [512][1024]
  __bf16* xbf   = (__bf16*)(ws + ((size_t)4 << 20));   // 32 MB [B][256][1024]
  __bf16* XnT   = (__bf16*)(ws + ((size_t)36 << 20));  // 32 MB [B][512][512]
  __bf16* Y1T   = (__bf16*)(ws + ((size_t)68 << 20));  // 32 MB [B][512][512]
  __bf16* Z1T   = (__bf16*)(ws + ((size_t)100 << 20)); // 16 MB [B][512][256]
  __bf16* Z3T   = (__bf16*)(ws + ((size_t)116 << 20)); // 16 MB -> 132 MB total

  // L1: stats partials + xbf cast + all weight prep
  pre1_k<<<4864, 256, 0, stream>>>(x, part, xbf, w1, w2, w3, w4, cw,
                                   w1b, w2b, w3b, w4b, WtT);
  // L2: G3 (xbf @ WtT -> Z1T) || norm (x -> XnT, stats folded in)
  fused_g3_norm_k<<<4608, 256, 0, stream>>>(xbf, WtT, Z1T, cb, x, g, be, part, XnT);
  // L3: G1 (w1 @ Xn -> Y1T) || G4 (w3 @ Z1 -> Z3T)
  fused_g1_g4_k<<<1536, 256, 0, stream>>>(w1b, XnT, Y1T, b1, w3b, Z1T, Z3T, b3);
  // L4: G2 (w2 @ Y1 -> out[:,:,0:512]) || G5 (w4 @ Z3 -> out[:,:,512:768])
  fused_g2_g5_k<<<1536, 256, 0, stream>>>(w2b, Y1T, out, b2, w4b, Z3T, b4);
}

// Round 6
// 130.086 us; speedup vs baseline: 6.0262x; 1.0222x over previous
//
#include <hip/hip_runtime.h>
#include <hip/hip_bf16.h>

// MultiScaleTimeMixer: B=64, T=512, C=512, T2=256
// bf16 MFMA pipeline, intermediates TRANSPOSED ([N x K] for next GEMM).
// R6: tril K-truncation (Keff = bm+128 for masked GEMMs; skipped tiles are
//     exactly zero in pre-masked A -> bit-identical). DAG: pre1 -> [G3|norm]
//     -> [G1|G4] -> [G2|G5].

#define NB 64

typedef __bf16 bf16x8 __attribute__((ext_vector_type(8)));
typedef __bf16 bf16x4 __attribute__((ext_vector_type(4)));
typedef float f32x4 __attribute__((ext_vector_type(4)));

#define AS_GLOBAL __attribute__((address_space(1)))
#define AS_LDS    __attribute__((address_space(3)))

// ---- fused: per-batch partial stats + xbf cast (blocks 0..255) + weight prep ----
__global__ void pre1_k(const float* __restrict__ x, float* __restrict__ part,
                       __bf16* __restrict__ xbf,
                       const float* __restrict__ w1, const float* __restrict__ w2,
                       const float* __restrict__ w3, const float* __restrict__ w4,
                       const float* __restrict__ cw,
                       __bf16* __restrict__ w1b, __bf16* __restrict__ w2b,
                       __bf16* __restrict__ w3b, __bf16* __restrict__ w4b,
                       __bf16* __restrict__ WtT) {
  if (blockIdx.x < 256) {
    int bb = blockIdx.x;  // 4 per batch
    int b = bb >> 2, q = bb & 3;
    size_t base = (size_t)b * 262144 + (size_t)q * 65536;
    const float4* xb = (const float4*)(x + base);
    bf16x4* xo = (bf16x4*)(xbf + base);
    float s = 0.f, ss = 0.f;
    for (int it = 0; it < 64; ++it) {
      int idx = threadIdx.x + 256 * it;
      float4 v = xb[idx];
      s += (v.x + v.y) + (v.z + v.w);
      ss += (v.x * v.x + v.y * v.y) + (v.z * v.z + v.w * v.w);
      bf16x4 o;
      o[0] = (__bf16)v.x; o[1] = (__bf16)v.y; o[2] = (__bf16)v.z; o[3] = (__bf16)v.w;
      xo[idx] = o;
    }
    __shared__ float ls[256], lss[256];
    ls[threadIdx.x] = s; lss[threadIdx.x] = ss;
    __syncthreads();
    for (int off = 128; off > 0; off >>= 1) {
      if (threadIdx.x < off) {
        ls[threadIdx.x] += ls[threadIdx.x + off];
        lss[threadIdx.x] += lss[threadIdx.x + off];
      }
      __syncthreads();
    }
    if (threadIdx.x == 0) { part[bb * 2] = ls[0]; part[bb * 2 + 1] = lss[0]; }
    return;
  }
  int idx = (blockIdx.x - 256) * 256 + threadIdx.x;
  if (idx < 262144) { int i = idx >> 9, j = idx & 511; w1b[idx] = (__bf16)(j <= i ? w1[idx] : 0.f); return; }
  idx -= 262144;
  if (idx < 262144) { int i = idx >> 9, j = idx & 511; w2b[idx] = (__bf16)(j <= i ? w2[idx] : 0.f); return; }
  idx -= 262144;
  if (idx < 65536) { int i = idx >> 8, j = idx & 255; w3b[idx] = (__bf16)(j <= i ? w3[idx] : 0.f); return; }
  idx -= 65536;
  if (idx < 65536) { int i = idx >> 8, j = idx & 255; w4b[idx] = (__bf16)(j <= i ? w4[idx] : 0.f); return; }
  idx -= 65536;
  // WtT[o][k*512+i] = cw[o][i*2+k]   (B^T layout [512][1024])
  int o = idx >> 10, r = idx & 1023;
  int i = r & 511, k = r >> 9;
  WtT[idx] = (__bf16)cw[(size_t)o * 1024 + i * 2 + k];
}

// ---------------- GEMM body: A [MxK] rm, Bt [NxK] rm (bf16); D^T store ----------------
// LDS: row r (128B), 16B-chunk s holds global chunk s ^ (r&7); gload_lds linear dest,
// source pre-swizzled (rule #21). XCD-chunked swizzle, runtime lgx (nwg%8==0).
// MASKK: A is lower-triangular (pre-masked) -> truncate K at bm+128 (exact).
template <bool MASKK, bool HSW, bool ROWB, bool COLB, bool OUTBF>
__device__ __forceinline__ void gemm_body(
    int bid, int lgx, __bf16* As, __bf16* Bs,
    const __bf16* __restrict__ A, long sAb,
    const __bf16* __restrict__ Bt, long sBb,
    void* __restrict__ Cm, long sCb,
    const float* __restrict__ bias,
    int K, int ldc, int c_off) {
  const int tid = threadIdx.x;
  const int lane = tid & 63, wid = tid >> 6;
  const int wm = (wid >> 1) * 64, wn = (wid & 1) * 64;
  const int lr = lane & 15, lg = lane >> 4;

  const int nid = ((bid & 7) << (lgx + 5)) | (bid >> 3);
  const int bm = (nid & ((1 << lgx) - 1)) * 128;
  const int bn = ((nid >> lgx) & 3) * 128;
  const int bz = nid >> (lgx + 2);

  const int srg = lane >> 3;                  // row within 8-row group == (row&7)
  const int ssrc = ((lane & 7) ^ srg) << 3;   // pre-swizzled source chunk (elems)

  const __bf16* gA[4];
  const __bf16* gB[4];
#pragma unroll
  for (int p = 0; p < 4; ++p) {
    int row = p * 32 + wid * 8 + srg;
    gA[p] = A + (size_t)bz * sAb + (size_t)(bm + row) * K + ssrc;
    gB[p] = Bt + (size_t)bz * sBb + (size_t)(bn + row) * K + ssrc;
  }

  f32x4 acc[4][4] = {};

  const int Kend = MASKK ? (bm + 128) : K;   // tril: k >= bm+128 hits zeros in A
  for (int k0 = 0; k0 < Kend; k0 += 64) {
#pragma unroll
    for (int p = 0; p < 4; ++p) {
      __builtin_amdgcn_global_load_lds(
          (const AS_GLOBAL void*)gA[p],
          (AS_LDS void*)&As[(p * 32 + wid * 8) * 64], 16, 0, 0);
      __builtin_amdgcn_global_load_lds(
          (const AS_GLOBAL void*)gB[p],
          (AS_LDS void*)&Bs[(p * 32 + wid * 8) * 64], 16, 0, 0);
      gA[p] += 64;
      gB[p] += 64;
    }
    __syncthreads();
#pragma unroll
    for (int kk = 0; kk < 64; kk += 32) {
      bf16x8 af[4], bfv[4];
#pragma unroll
      for (int f = 0; f < 4; ++f) {
        int ar = wm + f * 16 + lr;
        af[f] = *(const bf16x8*)&As[ar * 64 + ((kk + lg * 8) ^ ((ar & 7) << 3))];
        int br = wn + f * 16 + lr;
        bfv[f] = *(const bf16x8*)&Bs[br * 64 + ((kk + lg * 8) ^ ((br & 7) << 3))];
      }
#pragma unroll
      for (int i = 0; i < 4; ++i)
#pragma unroll
        for (int j = 0; j < 4; ++j)
          acc[i][j] = __builtin_amdgcn_mfma_f32_16x16x32_bf16(af[i], bfv[j], acc[i][j], 0, 0, 0);
    }
    __syncthreads();
  }

  // epilogue: D[row][col]: col = lane&15 (+16j), row = (lane>>4)*4+r (+16i). store D^T.
#pragma unroll
  for (int i = 0; i < 4; ++i) {
    int row0 = bm + wm + i * 16 + lg * 4;
    float rb0 = 0.f, rb1 = 0.f, rb2 = 0.f, rb3 = 0.f;
    if (ROWB) { rb0 = bias[row0]; rb1 = bias[row0 + 1]; rb2 = bias[row0 + 2]; rb3 = bias[row0 + 3]; }
#pragma unroll
    for (int j = 0; j < 4; ++j) {
      int col = bn + wn + j * 16 + lr;
      float cbv = COLB ? bias[col] : 0.f;
      float v[4] = {acc[i][j][0] + rb0 + cbv, acc[i][j][1] + rb1 + cbv,
                    acc[i][j][2] + rb2 + cbv, acc[i][j][3] + rb3 + cbv};
      if (HSW) {
#pragma unroll
        for (int r = 0; r < 4; ++r) {
          float u = fminf(fmaxf(v[r] + 3.f, 0.f), 6.f);
          v[r] = v[r] * u * (1.f / 6.f);
        }
      }
      if (OUTBF) {
        __bf16* C = (__bf16*)Cm + (size_t)bz * sCb;
        bf16x4 o;
        o[0] = (__bf16)v[0]; o[1] = (__bf16)v[1]; o[2] = (__bf16)v[2]; o[3] = (__bf16)v[3];
        *(bf16x4*)&C[(size_t)col * ldc + c_off + row0] = o;
      } else {
        float* C = (float*)Cm + (size_t)bz * sCb;
        *(float4*)&C[(size_t)col * ldc + c_off + row0] =
            make_float4(v[0], v[1], v[2], v[3]);
      }
    }
  }
}

// ---- norm body: XnT[b][c][t] = bf16(((x-mean)*istd)*g + be), 64x64 tile ----
__device__ __forceinline__ void norm_body(
    int bid, char* smem,
    const float* __restrict__ x, const float* __restrict__ g,
    const float* __restrict__ be, const float* __restrict__ part,
    __bf16* __restrict__ XnT) {
  float (*ls)[65] = (float(*)[65])smem;
  int b = bid >> 6;
  int r = bid & 63;
  int bc = (r & 7) * 64;   // c tile
  int bt = (r >> 3) * 64;  // t tile
  int tid = threadIdx.x;
  float s = 0.f, ss = 0.f;
#pragma unroll
  for (int q = 0; q < 4; ++q) { s += part[(b * 4 + q) * 2]; ss += part[(b * 4 + q) * 2 + 1]; }
  float mean = s * (1.f / 262144.f);
  float istd = rsqrtf(ss * (1.f / 262144.f) - mean * mean + 1e-5f);

  const float* xb = x + (size_t)b * 262144;
  int r0 = tid >> 4;
  int c4 = (tid & 15) * 4;
#pragma unroll
  for (int p = 0; p < 4; ++p) {
    int t = p * 16 + r0;
    float4 v = *(const float4*)&xb[(size_t)(bt + t) * 512 + bc + c4];
    ls[t][c4] = v.x; ls[t][c4 + 1] = v.y; ls[t][c4 + 2] = v.z; ls[t][c4 + 3] = v.w;
  }
  __syncthreads();
  int cr = tid >> 3;
  int t0 = (tid & 7) * 8;
  __bf16* xnb = XnT + (size_t)b * 262144;
#pragma unroll
  for (int p = 0; p < 2; ++p) {
    int cg = bc + p * 32 + cr;
    int cl = p * 32 + cr;
    float4 g0 = *(const float4*)&g[(size_t)cg * 512 + bt + t0];
    float4 g1 = *(const float4*)&g[(size_t)cg * 512 + bt + t0 + 4];
    float4 e0 = *(const float4*)&be[(size_t)cg * 512 + bt + t0];
    float4 e1 = *(const float4*)&be[(size_t)cg * 512 + bt + t0 + 4];
    float gv[8] = {g0.x, g0.y, g0.z, g0.w, g1.x, g1.y, g1.z, g1.w};
    float ev[8] = {e0.x, e0.y, e0.z, e0.w, e1.x, e1.y, e1.z, e1.w};
    bf16x8 o;
#pragma unroll
    for (int j = 0; j < 8; ++j) {
      float xh = (ls[t0 + j][cl] - mean) * istd;
      o[j] = (__bf16)(xh * gv[j] + ev[j]);
    }
    *(bf16x8*)&xnb[(size_t)cg * 512 + bt + t0] = o;
  }
}

// ---- L2: G3 (conv-as-GEMM, blocks 0..511) | norm (blocks 512..4607) ----
__global__ __launch_bounds__(256, 3) void fused_g3_norm_k(
    const __bf16* __restrict__ xbf, const __bf16* __restrict__ WtT,
    __bf16* __restrict__ Z1T, const float* __restrict__ cb,
    const float* __restrict__ x, const float* __restrict__ g,
    const float* __restrict__ be, const float* __restrict__ part,
    __bf16* __restrict__ XnT) {
  __shared__ __align__(16) char smem[33280];
  __bf16* As = (__bf16*)smem;
  __bf16* Bs = (__bf16*)(smem + 16384);
  int bid = blockIdx.x;
  if (bid < 512) {
    gemm_body<false, false, false, true, true>(bid, 1, As, Bs,
        xbf, 262144, WtT, 0, Z1T, 131072, cb, 1024, 256, 0);
  } else {
    norm_body(bid - 512, smem, x, g, be, part, XnT);
  }
}

// ---- L3: G1 (blocks 0..1023) | G4 (blocks 1024..1535) ----
__global__ __launch_bounds__(256, 3) void fused_g1_g4_k(
    const __bf16* __restrict__ w1b, const __bf16* __restrict__ XnT,
    __bf16* __restrict__ Y1T, const float* __restrict__ b1,
    const __bf16* __restrict__ w3b, const __bf16* __restrict__ Z1T,
    __bf16* __restrict__ Z3T, const float* __restrict__ b3) {
  __shared__ __align__(16) char smem[32768];
  __bf16* As = (__bf16*)smem;
  __bf16* Bs = (__bf16*)(smem + 16384);
  int bid = blockIdx.x;
  if (bid < 1024)
    gemm_body<true, true, true, false, true>(bid, 2, As, Bs,
        w1b, 0, XnT, 262144, Y1T, 262144, b1, 512, 512, 0);
  else
    gemm_body<true, true, true, false, true>(bid - 1024, 1, As, Bs,
        w3b, 0, Z1T, 131072, Z3T, 131072, b3, 256, 256, 0);
}

// ---- L4: G2 (blocks 0..1023) | G5 (blocks 1024..1535) ----
__global__ __launch_bounds__(256, 3) void fused_g2_g5_k(
    const __bf16* __restrict__ w2b, const __bf16* __restrict__ Y1T,
    float* __restrict__ out, const float* __restrict__ b2,
    const __bf16* __restrict__ w4b, const __bf16* __restrict__ Z3T,
    const float* __restrict__ b4) {
  __shared__ __align__(16) char smem[32768];
  __bf16* As = (__bf16*)smem;
  __bf16* Bs = (__bf16*)(smem + 16384);
  int bid = blockIdx.x;
  if (bid < 1024)
    gemm_body<true, false, true, false, false>(bid, 2, As, Bs,
        w2b, 0, Y1T, 262144, out, 393216, b2, 512, 768, 0);
  else
    gemm_body<true, false, true, false, false>(bid - 1024, 1, As, Bs,
        w4b, 0, Z3T, 131072, out, 393216, b4, 256, 768, 512);
}

extern "C" void kernel_launch(void* const* d_in, const int* in_sizes, int n_in,
                              void* d_out, int out_size, void* d_ws, size_t ws_size,
                              hipStream_t stream) {
  const float* x  = (const float*)d_in[0];
  const float* g  = (const float*)d_in[1];
  const float* be = (const float*)d_in[2];
  const float* w1 = (const float*)d_in[3];
  const float* b1 = (const float*)d_in[4];
  const float* w2 = (const float*)d_in[5];
  const float* b2 = (const float*)d_in[6];
  const float* cw = (const float*)d_in[7];
  const float* cb = (const float*)d_in[8];
  const float* w3 = (const float*)d_in[9];
  const float* b3 = (const float*)d_in[10];
  const float* w4 = (const float*)d_in[11];
  const float* b4 = (const float*)d_in[12];
  float* out = (float*)d_out;

  char* ws = (char*)d_ws;
  float*  part  = (float*)(ws + 4096);                 // 2 KB
  __bf16* w1b   = (__bf16*)(ws + (1 << 20));           // 512 KB
  __bf16* w2b   = (__bf16*)(ws + (1 << 20) + 524288);
  __bf16* w3b   = (__bf16*)(ws + (2 << 20));           // 128 KB
  __bf16* w4b   = (__bf16*)(ws + (2 << 20) + 131072);
  __bf16* WtT   = (__bf16*)(ws + (3 << 20));           // 1 MB   [512][1024]
  __bf16* xbf   = (__bf16*)(ws + ((size_t)4 << 20));   // 32 MB [B][256][1024]
  __bf16* XnT   = (__bf16*)(ws + ((size_t)36 << 20));  // 32 MB [B][512][512]
  __bf16* Y1T   = (__bf16*)(ws + ((size_t)68 << 20));  // 32 MB [B][512][512]
  __bf16* Z1T   = (__bf16*)(ws + ((size_t)100 << 20)); // 16 MB [B][512][256]
  __bf16* Z3T   = (__bf16*)(ws + ((size_t)116 << 20)); // 16 MB -> 132 MB total

  // L1: stats partials + xbf cast + all weight prep
  pre1_k<<<4864, 256, 0, stream>>>(x, part, xbf, w1, w2, w3, w4, cw,
                                   w1b, w2b, w3b, w4b, WtT);
  // L2: G3 (xbf @ WtT -> Z1T) || norm (x -> XnT, stats folded in)
  fused_g3_norm_k<<<4608, 256, 0, stream>>>(xbf, WtT, Z1T, cb, x, g, be, part, XnT);
  // L3: G1 (w1 @ Xn -> Y1T) || G4 (w3 @ Z1 -> Z3T)
  fused_g1_g4_k<<<1536, 256, 0, stream>>>(w1b, XnT, Y1T, b1, w3b, Z1T, Z3T, b3);
  // L4: G2 (w2 @ Y1 -> out[:,:,0:512]) || G5 (w4 @ Z3 -> out[:,:,512:768])
  fused_g2_g5_k<<<1536, 256, 0, stream>>>(w2b, Y1T, out, b2, w4b, Z3T, b4);
}